// Round 9
// baseline (36.845 us; speedup 1.0000x reference)
//
#include <hip/hip_runtime.h>
#include <hip/hip_bf16.h>

// B=64, N=8192. Output: concat(feats_final (B,N,2), feats_sparse (B,N,2)) f32.
// Single fused kernel: chain-scan (G_ii) + 3-layer conv stack via f16 MFMA.
// R9: 256-thread blocks, TSEG=512, CHK=128 -> ~36 KB LDS -> 4 independent
// blocks/CU (4-way phase slide vs R8's 2) to attack barrier lockstep.

#define BB 64
#define NN 8192
#define KWARM 64          // warm-up steps (contraction kills seed error)
#define TSEG 512          // output positions per block
#define H 8               // xsp halo each side (conv needs 6)
#define PCH 4             // positions emitted per chain thread
#define NCH 132           // (TSEG+2H)/PCH chain threads
#define STG0 160          // first staging thread
#define CHK 128           // conv chunk size
#define NT 256            // threads (4 waves)
#define HST 40            // h-tile row stride in ushorts (80 B; (5r+q)%8 bijective)

using half8  = __attribute__((ext_vector_type(8))) _Float16;
using f32x16 = __attribute__((ext_vector_type(16))) float;
using f32x4  = __attribute__((ext_vector_type(4))) float;

__device__ __forceinline__ half8 ld16(const ushort* p) {   // one ds_read_b128
    return *reinterpret_cast<const half8*>(p);
}
__device__ __forceinline__ half8 ld8(const ushort* p) {    // two ds_read_b64
    union { half8 v; unsigned long long q[2]; } u;
    u.q[0] = *reinterpret_cast<const unsigned long long*>(p);
    u.q[1] = *reinterpret_cast<const unsigned long long*>(p + 4);
    return u.v;
}
__device__ __forceinline__ ushort f2h(float x) {
    _Float16 h = (_Float16)x;
    return __builtin_bit_cast(unsigned short, h);
}

// chain step with explicit a-value: X <- (z - a) - 1/X, z = i
#define CSTV(RV, IV, AV) { float dd_ = RV*RV + IV*IV;                      \
    float iv_ = __builtin_amdgcn_rcpf(dd_);                                \
    float nr_ = -(AV) - RV*iv_;                                            \
    IV = 1.0f + IV*iv_; RV = nr_; }
// G = 1/(L + R - (z - a)), times mask
#define GC(LRV, LIV, RRV, RIV, AV, MM, GR, GI) {                           \
    float Dr_ = LRV + RRV + (AV), Di_ = LIV + RIV - 1.0f;                  \
    float iv_ = __builtin_amdgcn_rcpf(Dr_*Dr_ + Di_*Di_);                  \
    GR = Dr_*iv_*(MM); GI = -Di_*iv_*(MM); }

__global__ __launch_bounds__(NT, 4) void fused_kernel(
    const float* __restrict__ v,  const float* __restrict__ mask,
    const float* __restrict__ w1, const float* __restrict__ b1,
    const float* __restrict__ w2, const float* __restrict__ b2,
    const float* __restrict__ w3, const float* __restrict__ b3,
    float* __restrict__ outF, float* __restrict__ fs)
{
    __shared__ __align__(16) ushort h1t[136 * HST];  // [row rel c-4][ci]; aliases sa
    __shared__ __align__(16) ushort h2t[132 * HST];  // [row rel c-2][ci]
    __shared__ __align__(16) ushort wt1c[512];       // [co][k=kk*2+ci], pad k>=10
    __shared__ __align__(16) ushort wt2c[32 * 160];  // [co][k=kk*32+ci]
    __shared__ __align__(16) ushort wt3c[2 * 160];
    __shared__ __align__(16) uint   xsp[TSEG + 2*H]; // f16 (x0,x1) at pos s-8+i
    __shared__ __align__(4) unsigned char mskb[TSEG];
    __shared__ float b1s[32], b2s[32], b3s[2];

    const int tid  = threadIdx.x;
    const int b    = blockIdx.y;
    const int s    = blockIdx.x * TSEG;
    const int base = s - H - KWARM;                  // sa[p-base] = v[p]-2

    float* sa = reinterpret_cast<float*>(h1t);       // phase-A alias (2624 B)

    // ---- stage v (clamped; clamped entries only feed discarded warm-up) ----
    for (int i = tid; i < TSEG + 2*H + 2*KWARM; i += NT) {
        int g = base + i; g = min(max(g, 0), NN - 1);
        sa[i] = v[b * NN + g] - 2.0f;
    }
    __syncthreads();

    // ---- phase A: chains (threads 0..131) || weight staging (160..255) ----
    if (tid < NCH) {
        const int e0 = s - H + PCH * tid;
        if (e0 >= 0 && e0 + PCH <= NN) {
            float4 mv = *reinterpret_cast<const float4*>(&mask[b * NN + e0]);
            float Lr, Li, Rr, Ri;
            const bool fast = (e0 - KWARM >= 0) && (e0 + 3 + KWARM <= NN - 1);
            if (fast) {
                // interleaved L (ascending) + R (descending) warm-up,
                // float4 LDS reads, two independent rcp chains (ILP=2)
                const int i0 = e0 - KWARM - base;        // multiple of 4
                const int i1 = i0 + 131;
                const float4* s4 = reinterpret_cast<const float4*>(sa);
                float4 cL = s4[i0 >> 2];
                float4 cR = s4[(i1 - 3) >> 2];
                Lr = -cL.x; Li = 1.0f; Rr = -cR.w; Ri = 1.0f;
                CSTV(Lr, Li, cL.y); CSTV(Rr, Ri, cR.z);
                CSTV(Lr, Li, cL.z); CSTV(Rr, Ri, cR.y);
                CSTV(Lr, Li, cL.w); CSTV(Rr, Ri, cR.x);
                for (int g = 1; g <= 15; ++g) {
                    float4 nL = s4[(i0 + 4 * g) >> 2];
                    float4 nR = s4[(i1 - 3 - 4 * g) >> 2];
                    CSTV(Lr, Li, nL.x); CSTV(Rr, Ri, nR.w);
                    CSTV(Lr, Li, nL.y); CSTV(Rr, Ri, nR.z);
                    CSTV(Lr, Li, nL.z); CSTV(Rr, Ri, nR.y);
                    CSTV(Lr, Li, nL.w); CSTV(Rr, Ri, nR.x);
                }
                CSTV(Lr, Li, sa[i0 + 64]);   // L now at e0
                CSTV(Rr, Ri, sa[i0 + 67]);   // R now at e0+3
            } else {
                int j0 = max(e0 - KWARM, 0);
                Lr = -sa[j0 - base]; Li = 1.0f;
                for (int j = j0 + 1; j <= e0; ++j) CSTV(Lr, Li, sa[j - base]);
                int j1 = min(e0 + 3 + KWARM, NN - 1);
                Rr = -sa[j1 - base]; Ri = 1.0f;
                for (int j = j1 - 1; j >= e0 + 3; --j) CSTV(Rr, Ri, sa[j - base]);
            }
            // emit tail
            float a0v = sa[e0 - base],     a1v = sa[e0 + 1 - base];
            float a2v = sa[e0 + 2 - base], a3v = sa[e0 + 3 - base];
            float L0r = Lr, L0i = Li;
            CSTV(Lr, Li, a1v); float L1r = Lr, L1i = Li;
            CSTV(Lr, Li, a2v); float L2r = Lr, L2i = Li;
            CSTV(Lr, Li, a3v); float L3r = Lr, L3i = Li;
            float g0r,g0i,g1r,g1i,g2r,g2i,g3r,g3i;
            GC(L3r, L3i, Rr, Ri, a3v, mv.w, g3r, g3i);
            CSTV(Rr, Ri, a2v); GC(L2r, L2i, Rr, Ri, a2v, mv.z, g2r, g2i);
            CSTV(Rr, Ri, a1v); GC(L1r, L1i, Rr, Ri, a1v, mv.y, g1r, g1i);
            CSTV(Rr, Ri, a0v); GC(L0r, L0i, Rr, Ri, a0v, mv.x, g0r, g0i);

            uint4 pk;
            pk.x = (uint)f2h(g0r) | ((uint)f2h(g0i) << 16);
            pk.y = (uint)f2h(g1r) | ((uint)f2h(g1i) << 16);
            pk.z = (uint)f2h(g2r) | ((uint)f2h(g2i) << 16);
            pk.w = (uint)f2h(g3r) | ((uint)f2h(g3i) << 16);
            *reinterpret_cast<uint4*>(&xsp[PCH * tid]) = pk;

            if (e0 >= s && e0 < s + TSEG) {          // own (non-halo) positions
                float4 oa = make_float4(g0r, g0i, g1r, g1i);
                float4 ob = make_float4(g2r, g2i, g3r, g3i);
                size_t off = ((size_t)b * NN + e0) * 2;
                *reinterpret_cast<float4*>(&fs[off])       = oa;
                *reinterpret_cast<float4*>(&fs[off + 4])   = ob;
                *reinterpret_cast<float4*>(&outF[off])     = oa;   // default: fs
                *reinterpret_cast<float4*>(&outF[off + 4]) = ob;
                uint mb = (mv.x > 0.5f ? 1u : 0u) | (mv.y > 0.5f ? 1u : 0u) << 8
                        | (mv.z > 0.5f ? 1u : 0u) << 16 | (mv.w > 0.5f ? 1u : 0u) << 24;
                *reinterpret_cast<uint*>(&mskb[e0 - s]) = mb;
            }
        } else {
            uint4 z = {0u, 0u, 0u, 0u};              // zero 'same' padding
            *reinterpret_cast<uint4*>(&xsp[PCH * tid]) = z;
        }
    } else if (tid >= STG0) {
        const int t0 = tid - STG0;                   // 96 staging threads
        for (int i = t0; i < 512; i += 96) {
            int co = i >> 4, k = i & 15;
            wt1c[i] = (k < 10) ? f2h(w1[co*10 + (k&1)*5 + (k>>1)]) : (ushort)0;
        }
        for (int i = t0; i < 5120; i += 96) {
            int co = i / 160, k = i % 160;
            wt2c[i] = f2h(w2[co*160 + (k&31)*5 + (k>>5)]);
        }
        for (int i = t0; i < 320; i += 96) {
            int co = i / 160, k = i % 160;
            wt3c[i] = f2h(w3[co*160 + (k&31)*5 + (k>>5)]);
        }
        if (t0 < 32) { b1s[t0] = b1[t0]; b2s[t0] = b2[t0]; if (t0 < 2) b3s[t0] = b3[t0]; }
    }
    __syncthreads();
    // sa (aliased with h1t) is dead from here on.

    const int lane = tid & 63;
    const int wv   = tid >> 6;        // 0..3
    const int cn   = lane & 31;
    const int kh   = lane >> 5;
    const int ml   = lane & 15;       // conv3 16x16: A-row / C-col
    const int kg   = lane >> 4;       // conv3 16x16: k-group 0..3

    // persistent B-fragments (bw3 reloaded per chunk to cut VGPR pressure)
    half8 bw1 = ld8(&wt1c[cn * 16 + 8 * kh]);
    half8 bw[10];
    #pragma unroll
    for (int t = 0; t < 10; ++t) bw[t] = ld16(&wt2c[cn*160 + 16*t + 8*kh]);

    for (int ch = 0; ch < 4; ++ch) {
        const int cr = ch * CHK;      // chunk base rel s

        // ---- conv1: 5 tiles (rows rel c-4: 0..135); wave0 also does tile 4
        {
            #pragma unroll
            for (int pass = 0; pass < 2; ++pass) {
                int t = (pass == 0) ? wv : ((wv == 0) ? 4 : -1);
                if (t >= 0) {
                    int tb1 = (t < 4) ? 32*t : 104;
                    int x0  = cr + 2 + tb1 + cn;     // xsp idx: (c-s)+2+row+kk
                    union { half8 v8; uint u[4]; } A;
                    if (kh == 0) { A.u[0]=xsp[x0]; A.u[1]=xsp[x0+1];
                                   A.u[2]=xsp[x0+2]; A.u[3]=xsp[x0+3]; }
                    else         { A.u[0]=xsp[x0+4]; A.u[1]=0; A.u[2]=0; A.u[3]=0; }
                    f32x16 a1 = {};
                    a1 = __builtin_amdgcn_mfma_f32_32x32x16_f16(A.v8, bw1, a1, 0, 0, 0);
                    float bias = b1s[cn];
                    #pragma unroll
                    for (int r = 0; r < 16; ++r) {
                        int m = (r&3) + 8*(r>>2) + 4*kh;
                        int row = tb1 + m;
                        int gp  = s + cr - 4 + row;
                        h1t[row*HST + cn] = (gp >= 0 && gp < NN)
                            ? f2h(fmaxf(a1[r] + bias, 0.f)) : (ushort)0;
                    }
                }
            }
        }
        __syncthreads();

        // ---- conv2: 5 tiles; single acc chain; b128 A-frags ----
        {
            #pragma unroll
            for (int pass = 0; pass < 2; ++pass) {
                int t = (pass == 0) ? wv : ((wv == 0) ? 4 : -1);
                if (t >= 0) {
                    int tb2 = (t < 4) ? 32*t : 100;
                    f32x16 acc = {};
                    #pragma unroll
                    for (int j = 0; j < 5; ++j) {
                        const ushort* rp = &h1t[(tb2 + cn + j)*HST + 8*kh];
                        acc = __builtin_amdgcn_mfma_f32_32x32x16_f16(ld16(rp),      bw[2*j],   acc, 0, 0, 0);
                        acc = __builtin_amdgcn_mfma_f32_32x32x16_f16(ld16(rp + 16), bw[2*j+1], acc, 0, 0, 0);
                    }
                    float bias = b2s[cn];
                    #pragma unroll
                    for (int r = 0; r < 16; ++r) {
                        int m = (r&3) + 8*(r>>2) + 4*kh;
                        int row = tb2 + m;
                        int gp  = s + cr - 2 + row;
                        h2t[row*HST + cn] = (gp >= 0 && gp < NN)
                            ? f2h(fmaxf(acc[r] + bias, 0.f)) : (ushort)0;
                    }
                }
            }
        }
        __syncthreads();

        // ---- conv3 via 16x16x32 MFMA (N=2 of 16); 2 tiles/wave; b128 A ----
        {
            int co_b = (ml < 2) ? ml : 0;
            half8 bw3[5];
            #pragma unroll
            for (int q = 0; q < 5; ++q)
                bw3[q] = ld16(&wt3c[co_b*160 + q*32 + kg*8]);
            #pragma unroll
            for (int t3i = 0; t3i < 2; ++t3i) {
                int rb = 16 * (2*wv + t3i);          // h2t row base
                f32x4 a3 = {};
                #pragma unroll
                for (int q = 0; q < 5; ++q) {
                    half8 av = ld16(&h2t[(rb + ml + q)*HST + kg*8]);
                    a3 = __builtin_amdgcn_mfma_f32_16x16x32_f16(av, bw3[q], a3, 0, 0, 0);
                }
                if (ml < 2) {
                    float bias = b3s[ml];
                    #pragma unroll
                    for (int r = 0; r < 4; ++r) {
                        int p = cr + rb + kg*4 + r;  // rel s
                        if (!mskb[p])
                            outF[((size_t)b*NN + s + p)*2 + ml] = a3[r] + bias;
                    }
                }
            }
        }
        // no barrier needed here: next conv1's post-barrier orders h1t/h2t reuse
    }
}

extern "C" void kernel_launch(void* const* d_in, const int* in_sizes, int n_in,
                              void* d_out, int out_size, void* d_ws, size_t ws_size,
                              hipStream_t stream) {
    const float* v    = (const float*)d_in[0];
    const float* mask = (const float*)d_in[1];
    const float* w1   = (const float*)d_in[2];
    const float* b1   = (const float*)d_in[3];
    const float* w2   = (const float*)d_in[4];
    const float* b2   = (const float*)d_in[5];
    const float* w3   = (const float*)d_in[6];
    const float* b3   = (const float*)d_in[7];

    float* outF = (float*)d_out;                  // feats_final (B,N,2)
    float* fs   = outF + (size_t)BB * NN * 2;     // feats_sparse (B,N,2)

    dim3 g(NN / TSEG, BB);                        // 16 x 64 = 1024 blocks
    fused_kernel<<<g, NT, 0, stream>>>(v, mask, w1, b1, w2, b2, w3, b3, outF, fs);
}

// Round 11
// 31.145 us; speedup vs baseline: 1.1830x; 1.1830x over previous
//
#include <hip/hip_runtime.h>
#include <hip/hip_bf16.h>

// B=64, N=8192. Output: concat(feats_final (B,N,2), feats_sparse (B,N,2)) f32.
// Fused: chain-scan (G_ii) + 3-layer conv via f16 MFMA, SWAPPED operands:
//   D[co][pos] = mfma(A=W-frag, B=H-frag): lane holds one position's 16
//   consecutive channels -> packed b64 LDS stores; bias folded into MFMA
//   via an extra K-slice against a ones-B-fragment.
// R11 fixes vs R10: RN f16 packing (RTZ was coherently biased through the
// conv stack -> 2.6e-2), KWARM back to 64, zero-init xsp tail pad.

#define BB 64
#define NN 8192
#define KWARM 64
#define TSEG 1024
#define H 8
#define PCH 4
#define NCH 260
#define STG0 320
#define CHK 256
#define NT 512
#define HST 40            // 80 B rows: bank-quad(row)=5r%8 bijective (b128 floor)

using half8  = __attribute__((ext_vector_type(8))) _Float16;
using f32x16 = __attribute__((ext_vector_type(16))) float;

__device__ __forceinline__ half8 ld16(const ushort* p) {   // ds_read_b128
    return *reinterpret_cast<const half8*>(p);
}
__device__ __forceinline__ ushort f2h(float x) {
    _Float16 h = (_Float16)x;
    return __builtin_bit_cast(unsigned short, h);
}
__device__ __forceinline__ uint pk2rn(float a, float b) {  // 2x cvt RN + pack
    union { _Float16 h[2]; uint u; } r;
    r.h[0] = (_Float16)a; r.h[1] = (_Float16)b;
    return r.u;
}

#define CSTV(RV, IV, AV) { float dd_ = RV*RV + IV*IV;                      \
    float iv_ = __builtin_amdgcn_rcpf(dd_);                                \
    float nr_ = -(AV) - RV*iv_;                                            \
    IV = 1.0f + IV*iv_; RV = nr_; }
#define GC(LRV, LIV, RRV, RIV, AV, MM, GR, GI) {                           \
    float Dr_ = LRV + RRV + (AV), Di_ = LIV + RIV - 1.0f;                  \
    float iv_ = __builtin_amdgcn_rcpf(Dr_*Dr_ + Di_*Di_);                  \
    GR = Dr_*iv_*(MM); GI = -Di_*iv_*(MM); }

__global__ __launch_bounds__(NT, 4) void fused_kernel(
    const float* __restrict__ v,  const float* __restrict__ mask,
    const float* __restrict__ w1, const float* __restrict__ b1,
    const float* __restrict__ w2, const float* __restrict__ b2,
    const float* __restrict__ w3, const float* __restrict__ b3,
    float* __restrict__ outF, float* __restrict__ fs)
{
    __shared__ __align__(16) ushort h1t[264 * HST];  // [row rel c-4][ci]; aliases sa
    __shared__ __align__(16) ushort h2t[260 * HST];  // [row rel c-2][ci]
    __shared__ __align__(16) ushort wt1c[32 * 32];   // [co][k]; k16=bias
    __shared__ __align__(16) ushort wt2c[32 * 176];  // [co][k=kk*32+ci]; k160=bias
    __shared__ __align__(16) ushort wt3c[2 * 176];   // k160=bias
    __shared__ __align__(16) ushort ones16[16];      // {1h,0...}|{0...}
    __shared__ __align__(16) uint   xsp[TSEG + 2*H + 8];
    __shared__ __align__(4) unsigned char mskb[TSEG];

    const int tid  = threadIdx.x;
    const int b    = blockIdx.y;
    const int s    = blockIdx.x * TSEG;
    const int base = s - H - KWARM;

    float* sa = reinterpret_cast<float*>(h1t);       // phase-A alias (4672 B)

    for (int i = tid; i < TSEG + 2*H + 2*KWARM; i += NT) {
        int g = base + i; g = min(max(g, 0), NN - 1);
        sa[i] = v[b * NN + g] - 2.0f;
    }
    __syncthreads();

    // ---- phase A: chains (0..259) || weight staging (320..511) ----
    if (tid < NCH) {
        const int e0 = s - H + PCH * tid;
        if (e0 >= 0 && e0 + PCH <= NN) {
            float4 mv = *reinterpret_cast<const float4*>(&mask[b * NN + e0]);
            float Lr, Li, Rr, Ri;
            const bool fast = (e0 - KWARM >= 0) && (e0 + 3 + KWARM <= NN - 1);
            if (fast) {
                const int i0 = e0 - KWARM - base;    // multiple of 4
                const float4* s4 = reinterpret_cast<const float4*>(sa);
                float4 cL = s4[i0 >> 2];
                float4 cR = s4[(i0 + 2*KWARM) >> 2];
                Lr = -cL.x; Li = 1.0f; Rr = -cR.w; Ri = 1.0f;
                CSTV(Lr, Li, cL.y); CSTV(Rr, Ri, cR.z);
                CSTV(Lr, Li, cL.z); CSTV(Rr, Ri, cR.y);
                CSTV(Lr, Li, cL.w); CSTV(Rr, Ri, cR.x);
                #pragma unroll
                for (int g = 1; g <= KWARM/4 - 1; ++g) {
                    float4 nL = s4[(i0 + 4*g) >> 2];
                    float4 nR = s4[(i0 + 2*KWARM - 4*g) >> 2];
                    CSTV(Lr, Li, nL.x); CSTV(Rr, Ri, nR.w);
                    CSTV(Lr, Li, nL.y); CSTV(Rr, Ri, nR.z);
                    CSTV(Lr, Li, nL.z); CSTV(Rr, Ri, nR.y);
                    CSTV(Lr, Li, nL.w); CSTV(Rr, Ri, nR.x);
                }
                CSTV(Lr, Li, sa[i0 + KWARM]);        // L at e0
                CSTV(Rr, Ri, sa[i0 + KWARM + 3]);    // R at e0+3
            } else {
                int j0 = max(e0 - KWARM, 0);
                Lr = -sa[j0 - base]; Li = 1.0f;
                for (int j = j0 + 1; j <= e0; ++j) CSTV(Lr, Li, sa[j - base]);
                int j1 = min(e0 + 3 + KWARM, NN - 1);
                Rr = -sa[j1 - base]; Ri = 1.0f;
                for (int j = j1 - 1; j >= e0 + 3; --j) CSTV(Rr, Ri, sa[j - base]);
            }
            float a0v = sa[e0 - base],     a1v = sa[e0 + 1 - base];
            float a2v = sa[e0 + 2 - base], a3v = sa[e0 + 3 - base];
            float L0r = Lr, L0i = Li;
            CSTV(Lr, Li, a1v); float L1r = Lr, L1i = Li;
            CSTV(Lr, Li, a2v); float L2r = Lr, L2i = Li;
            CSTV(Lr, Li, a3v); float L3r = Lr, L3i = Li;
            float g0r,g0i,g1r,g1i,g2r,g2i,g3r,g3i;
            GC(L3r, L3i, Rr, Ri, a3v, mv.w, g3r, g3i);
            CSTV(Rr, Ri, a2v); GC(L2r, L2i, Rr, Ri, a2v, mv.z, g2r, g2i);
            CSTV(Rr, Ri, a1v); GC(L1r, L1i, Rr, Ri, a1v, mv.y, g1r, g1i);
            CSTV(Rr, Ri, a0v); GC(L0r, L0i, Rr, Ri, a0v, mv.x, g0r, g0i);

            uint4 pk;
            pk.x = (uint)f2h(g0r) | ((uint)f2h(g0i) << 16);
            pk.y = (uint)f2h(g1r) | ((uint)f2h(g1i) << 16);
            pk.z = (uint)f2h(g2r) | ((uint)f2h(g2i) << 16);
            pk.w = (uint)f2h(g3r) | ((uint)f2h(g3i) << 16);
            *reinterpret_cast<uint4*>(&xsp[PCH * tid]) = pk;

            if (e0 >= s && e0 < s + TSEG) {
                float4 oa = make_float4(g0r, g0i, g1r, g1i);
                float4 ob = make_float4(g2r, g2i, g3r, g3i);
                size_t off = ((size_t)b * NN + e0) * 2;
                *reinterpret_cast<float4*>(&fs[off])       = oa;
                *reinterpret_cast<float4*>(&fs[off + 4])   = ob;
                *reinterpret_cast<float4*>(&outF[off])     = oa;
                *reinterpret_cast<float4*>(&outF[off + 4]) = ob;
                uint mb = (mv.x > 0.5f ? 1u : 0u) | (mv.y > 0.5f ? 1u : 0u) << 8
                        | (mv.z > 0.5f ? 1u : 0u) << 16 | (mv.w > 0.5f ? 1u : 0u) << 24;
                *reinterpret_cast<uint*>(&mskb[e0 - s]) = mb;
            }
        } else {
            uint4 z = {0u, 0u, 0u, 0u};
            *reinterpret_cast<uint4*>(&xsp[PCH * tid]) = z;
        }
    } else if (tid >= STG0) {
        const int t0 = tid - STG0;                   // 192 staging threads
        for (int i = t0; i < 1024; i += 192) {       // wt1c [co][32]
            int co = i >> 5, k = i & 31;
            ushort val = 0;
            if (k < 10)       val = f2h(w1[co*10 + (k&1)*5 + (k>>1)]);
            else if (k == 16) val = f2h(b1[co]);
            wt1c[i] = val;
        }
        for (int i = t0; i < 5632; i += 192) {       // wt2c [co][176]
            int co = i / 176, k = i % 176;
            ushort val = 0;
            if (k < 160)       val = f2h(w2[co*160 + (k&31)*5 + (k>>5)]);
            else if (k == 160) val = f2h(b2[co]);
            wt2c[i] = val;
        }
        for (int i = t0; i < 352; i += 192) {        // wt3c [2][176]
            int co = i / 176, k = i % 176;
            ushort val = 0;
            if (k < 160)       val = f2h(w3[co*160 + (k&31)*5 + (k>>5)]);
            else if (k == 160) val = f2h(b3[co]);
            wt3c[i] = val;
        }
        if (t0 < 16) ones16[t0] = (t0 == 0) ? (ushort)0x3C00 : (ushort)0;
        if (t0 < 8)  xsp[TSEG + 2*H + t0] = 0u;      // zero the tail pad
    }
    __syncthreads();
    // sa (aliased with h1t) dead from here.

    const int lane = tid & 63;
    const int wv   = tid >> 6;        // 0..7
    const int cn   = lane & 31;
    const int kh   = lane >> 5;
    const int kh4  = 4 * kh;

    // persistent A-fragments (weights)
    half8 wA1  = ld16(&wt1c[cn * 32 + 8 * kh]);       // conv1 k 0..15
    half8 wA1b = ld16(&wt1c[cn * 32 + 16 + 8 * kh]);  // conv1 bias slice
    half8 wA2[11];
    #pragma unroll
    for (int t = 0; t < 11; ++t) wA2[t] = ld16(&wt2c[cn*176 + 16*t + 8*kh]);
    half8 onesF = ld16(&ones16[8 * kh]);              // {1,0..} / {0..}

    for (int ch = 0; ch < 4; ++ch) {
        const int cr = ch * CHK;

        // ---- conv1: 9 tiles (waves 0..7 + wave0 tail at 232) ----
        #pragma unroll
        for (int pass = 0; pass < 2; ++pass) {
            int t = (pass == 0) ? wv : ((wv == 0) ? 8 : -1);
            if (t >= 0) {
                int tb1 = (t < 8) ? 32*t : 232;
                int mi  = cr + 2 + tb1 + cn;
                union { half8 v8; uint u[4]; } B;
                B.u[0] = xsp[mi + kh4];     B.u[1] = xsp[mi + kh4 + 1];
                B.u[2] = xsp[mi + kh4 + 2]; B.u[3] = xsp[mi + kh4 + 3];
                f32x16 a1 = {};
                a1 = __builtin_amdgcn_mfma_f32_32x32x16_f16(wA1,  B.v8,  a1, 0, 0, 0);
                a1 = __builtin_amdgcn_mfma_f32_32x32x16_f16(wA1b, onesF, a1, 0, 0, 0);
                int row = tb1 + cn;
                int gp  = s + cr - 4 + row;
                bool ok = (gp >= 0) && (gp < NN);
                ushort* rp = &h1t[row * HST + kh4];
                #pragma unroll
                for (int q = 0; q < 4; ++q) {
                    uint lo = pk2rn(fmaxf(a1[4*q+0], 0.f), fmaxf(a1[4*q+1], 0.f));
                    uint hi = pk2rn(fmaxf(a1[4*q+2], 0.f), fmaxf(a1[4*q+3], 0.f));
                    *reinterpret_cast<uint2*>(rp + 8*q) =
                        make_uint2(ok ? lo : 0u, ok ? hi : 0u);
                }
            }
        }
        __syncthreads();

        // ---- conv2: 9 tiles (waves 0..7 + wave1 tail at 228) ----
        #pragma unroll
        for (int pass = 0; pass < 2; ++pass) {
            int t = (pass == 0) ? wv : ((wv == 1) ? 8 : -1);
            if (t >= 0) {
                int tb2 = (t < 8) ? 32*t : 228;
                f32x16 acc = {};
                #pragma unroll
                for (int q = 0; q < 10; ++q) {
                    int kidx = 16*q + 8*kh;
                    half8 Bf = ld16(&h1t[(tb2 + cn + (kidx >> 5))*HST + (kidx & 31)]);
                    acc = __builtin_amdgcn_mfma_f32_32x32x16_f16(wA2[q], Bf, acc, 0, 0, 0);
                }
                acc = __builtin_amdgcn_mfma_f32_32x32x16_f16(wA2[10], onesF, acc, 0, 0, 0);
                int row = tb2 + cn;
                int gp  = s + cr - 2 + row;
                bool ok = (gp >= 0) && (gp < NN);
                ushort* rp = &h2t[row * HST + kh4];
                #pragma unroll
                for (int q = 0; q < 4; ++q) {
                    uint lo = pk2rn(fmaxf(acc[4*q+0], 0.f), fmaxf(acc[4*q+1], 0.f));
                    uint hi = pk2rn(fmaxf(acc[4*q+2], 0.f), fmaxf(acc[4*q+3], 0.f));
                    *reinterpret_cast<uint2*>(rp + 8*q) =
                        make_uint2(ok ? lo : 0u, ok ? hi : 0u);
                }
            }
        }
        __syncthreads();

        // ---- conv3: 8 tiles; lane(kh=0) -> one float2 masked store ----
        {
            const int tb3 = 32 * wv;
            f32x16 a3 = {};
            half8 z = {};
            #pragma unroll
            for (int q = 0; q < 10; ++q) {
                int kidx = 16*q + 8*kh;
                half8 Af = (cn < 2) ? ld16(&wt3c[cn*176 + 16*q + 8*kh]) : z;
                half8 Bf = ld16(&h2t[(tb3 + cn + (kidx >> 5))*HST + (kidx & 31)]);
                a3 = __builtin_amdgcn_mfma_f32_32x32x16_f16(Af, Bf, a3, 0, 0, 0);
            }
            {
                half8 Af = (cn < 2) ? ld16(&wt3c[cn*176 + 160 + 8*kh]) : z;
                a3 = __builtin_amdgcn_mfma_f32_32x32x16_f16(Af, onesF, a3, 0, 0, 0);
            }
            if (kh == 0) {
                int p = cr + tb3 + cn;
                if (!mskb[p]) {
                    *reinterpret_cast<float2*>(&outF[((size_t)b*NN + s + p)*2]) =
                        make_float2(a3[0], a3[1]);
                }
            }
        }
        // no barrier: next conv1 writes h1t only; its barrier orders h2t reuse
    }
}

extern "C" void kernel_launch(void* const* d_in, const int* in_sizes, int n_in,
                              void* d_out, int out_size, void* d_ws, size_t ws_size,
                              hipStream_t stream) {
    const float* v    = (const float*)d_in[0];
    const float* mask = (const float*)d_in[1];
    const float* w1   = (const float*)d_in[2];
    const float* b1   = (const float*)d_in[3];
    const float* w2   = (const float*)d_in[4];
    const float* b2   = (const float*)d_in[5];
    const float* w3   = (const float*)d_in[6];
    const float* b3   = (const float*)d_in[7];

    float* outF = (float*)d_out;                  // feats_final (B,N,2)
    float* fs   = outF + (size_t)BB * NN * 2;     // feats_sparse (B,N,2)

    dim3 g(NN / TSEG, BB);                        // 8 x 64 = 512 blocks
    fused_kernel<<<g, NT, 0, stream>>>(v, mask, w1, b1, w2, b2, w3, b3, outF, fs);
}